// Round 6
// baseline (255.655 us; speedup 1.0000x reference)
//
#include <hip/hip_runtime.h>
#include <hip/hip_bf16.h>

typedef unsigned short u16;
typedef __attribute__((ext_vector_type(8))) short short8v;   // 8 bf16 = 4 VGPR
typedef __attribute__((ext_vector_type(4))) float f32x4;     // mfma 16x16 acc
typedef __attribute__((ext_vector_type(16))) float f32x16;   // mfma 32x32 acc

#define Bb 4
#define Tt 2048
#define Cc 1024
#define Hh 16
#define C3 3072
#define Mm 8192

__device__ __forceinline__ u16 f2bf(float f) {
    union { __hip_bfloat16 h; u16 u; } r;
    r.h = __float2bfloat16(f);
    return r.u;
}
__device__ __forceinline__ unsigned int pk2(float a, float b) {
    union { __hip_bfloat162 h; unsigned int u; } r;
    r.h.x = __float2bfloat16(a);
    r.h.y = __float2bfloat16(b);
    return r.u;
}
__device__ __forceinline__ float exp2g(float x) {
#if __has_builtin(__builtin_amdgcn_exp2f)
    return __builtin_amdgcn_exp2f(x);
#else
    return exp2f(x);
#endif
}
__device__ __forceinline__ void plswap(unsigned int& a, unsigned int& b) {
#if __has_builtin(__builtin_amdgcn_permlane32_swap)
    typedef __attribute__((ext_vector_type(2))) unsigned int uint2v;
    uint2v r = __builtin_amdgcn_permlane32_swap(a, b, false, false);
    a = r.x; b = r.y;
#else
    asm volatile("v_permlane32_swap_b32 %0, %1" : "+v"(a), "+v"(b));
#endif
}
// global -> LDS direct (16B/lane). LDS dest: wave-uniform base + lane*16.
__device__ __forceinline__ void gload16(const void* g, void* l) {
    __builtin_amdgcn_global_load_lds(
        (const __attribute__((address_space(1))) unsigned int*)g,
        (__attribute__((address_space(3))) unsigned int*)l, 16, 0, 0);
}

// ---------- convert x f32 -> bf16 ----------
__global__ __launch_bounds__(256) void cvt_x(const float* __restrict__ in,
                                             u16* __restrict__ out) {
    int i = blockIdx.x * 256 + threadIdx.x;
    float4 v = reinterpret_cast<const float4*>(in)[i];
    ushort4 o;
    o.x = f2bf(v.x); o.y = f2bf(v.y); o.z = f2bf(v.z); o.w = f2bf(v.w);
    reinterpret_cast<ushort4*>(out)[i] = o;
}

// ---------- transpose+convert W [R][Ccols] f32 -> W^T [Ccols][R] bf16 ----------
__global__ __launch_bounds__(256) void wtrans(const float* __restrict__ in,
                                              u16* __restrict__ out,
                                              int R, int Ccols) {
    __shared__ float t[32][33];
    const int tx = threadIdx.x & 31, ty = threadIdx.x >> 5;  // 32x8
    const int bx = blockIdx.x, by = blockIdx.y;
    const int c = bx * 32 + tx;
#pragma unroll
    for (int j = 0; j < 4; ++j) {
        int r = by * 32 + ty + j * 8;
        t[ty + j * 8][tx] = in[(size_t)r * Ccols + c];
    }
    __syncthreads();
#pragma unroll
    for (int j = 0; j < 4; ++j) {
        int orow = bx * 32 + ty + j * 8;
        int oc   = by * 32 + tx;
        out[(size_t)orow * R + oc] = f2bf(t[tx][ty + j * 8]);
    }
}

// ---------- bf16 MFMA GEMM: C[M][N] = A[M][K] * BT[N][K]^T (unchanged) ----------
template <int OUTF32>
__global__ __launch_bounds__(256) void gemm_mfma(const u16* __restrict__ A,
                                                 const u16* __restrict__ BT,
                                                 void* __restrict__ Cout,
                                                 int M, int N, int K) {
    __shared__ u16 As[128 * 32];
    __shared__ u16 Bs[128 * 32];
    const int tid = threadIdx.x;
    const int w = tid >> 6, l = tid & 63;
    const int wr = w >> 1, wc = w & 1;
    const int g = l >> 4, q = l & 15;
    const int bm = blockIdx.x * 128, bn = blockIdx.y * 128;
    const int lrow = l >> 2;
    const int lcol = (l & 3) * 8;

    f32x4 acc[4][4] = {};
    const u16* Ap = A + (size_t)(bm + w * 32 + lrow) * K + lcol;
    const u16* Bp = BT + (size_t)(bn + w * 32 + lrow) * K + lcol;

    for (int k0 = 0; k0 < K; k0 += 32) {
        gload16(Ap + k0, &As[(w * 32) * 32]);
        gload16(Ap + (size_t)16 * K + k0, &As[(w * 32 + 16) * 32]);
        gload16(Bp + k0, &Bs[(w * 32) * 32]);
        gload16(Bp + (size_t)16 * K + k0, &Bs[(w * 32 + 16) * 32]);
        __syncthreads();
        short8v af[4], bf[4];
#pragma unroll
        for (int m = 0; m < 4; ++m)
            af[m] = *reinterpret_cast<const short8v*>(&As[(wr * 64 + m * 16 + q) * 32 + g * 8]);
#pragma unroll
        for (int n = 0; n < 4; ++n)
            bf[n] = *reinterpret_cast<const short8v*>(&Bs[(wc * 64 + n * 16 + q) * 32 + g * 8]);
#pragma unroll
        for (int m = 0; m < 4; ++m)
#pragma unroll
            for (int n = 0; n < 4; ++n)
                acc[m][n] = __builtin_amdgcn_mfma_f32_16x16x32_bf16(af[m], bf[n], acc[m][n], 0, 0, 0);
        __syncthreads();
    }

#pragma unroll
    for (int m = 0; m < 4; ++m)
#pragma unroll
        for (int n = 0; n < 4; ++n)
#pragma unroll
            for (int r = 0; r < 4; ++r) {
                int row = bm + wr * 64 + m * 16 + g * 4 + r;
                int col = bn + wc * 64 + n * 16 + q;
                if (OUTF32)
                    reinterpret_cast<float*>(Cout)[(size_t)row * N + col] = acc[m][n][r];
                else
                    reinterpret_cast<u16*>(Cout)[(size_t)row * N + col] = f2bf(acc[m][n][r]);
            }
}

// ---------- MFMA flash attention (causal) ----------
// 1024 blocks: bid -> (c, bh); waves 0,1 own chunk 31-c, waves 2,3 own chunk c
// (64 q each, balanced). KV step = 64 keys. K LDS [64][72] row-major dbuf;
// V^T LDS [64 d][72] dbuf staged via lane-pair shuffle (round-4-verified path).
__global__ __launch_bounds__(256, 4) void attn_mfma(const u16* __restrict__ qkv,
                                                    u16* __restrict__ y) {
    __shared__ u16 SM[18432];   // 36,864 B: K dbuf 2x4608 | V^T dbuf 2x4608
    const int tid = threadIdx.x;
    const int w = tid >> 6, l = tid & 63;
    const int q31 = l & 31, hi = l >> 5;
    const int bid = blockIdx.x;
    const int c = bid & 15, bh = bid >> 4;
    const int b = bh >> 4, h = bh & 15;
    const size_t tok0 = (size_t)b * Tt;

    const int cBig = 31 - c;
    const int nsteps = cBig + 1;             // 17..32 KV steps
    const int chunkw = (w < 2) ? cBig : c;   // wave's 64-q chunk
    const int q0w = chunkw * 64 + (w & 1) * 32;
    const int qlane = q0w + q31;

    const float C2 = 0.18033688011112042f;   // 0.125 * log2(e)
    const float THR = 44.361419555836499f;   // 8 / C2 (defer-max)

    // staging ids: 256 thr cover 64 keys x 8 d-segs (2 segs each)
    const int skey = tid >> 2;
    const int sseg = (tid & 3) * 2;
    const int koff = skey * 72 + sseg * 8;
    const int kp = skey >> 1;          // V^T dword column
    const int veo = (skey & 1) * 4;    // e-range split by key parity
    const u16* gsrc = qkv + (tok0 + skey) * C3 + 1024 + h * 64 + sseg * 8;

    // Q fragments (mfma B operand): lane holds Q[q=l&31][d = 16s + 8hi + j]
    short8v qf0, qf1, qf2, qf3;
    {
        const u16* qp = qkv + (tok0 + qlane) * C3 + h * 64 + hi * 8;
        qf0 = *reinterpret_cast<const short8v*>(qp);
        qf1 = *reinterpret_cast<const short8v*>(qp + 16);
        qf2 = *reinterpret_cast<const short8v*>(qp + 32);
        qf3 = *reinterpret_cast<const short8v*>(qp + 48);
    }

    f32x16 acc0 = {}, acc1 = {};
    float m_run = -1e30f, l_run = 0.f;

    // ---- prologue: stage tile 0 into buf 0 ----
    {
        uint4 ka = *reinterpret_cast<const uint4*>(gsrc);
        uint4 kb = *reinterpret_cast<const uint4*>(gsrc + 8);
        uint4 va = *reinterpret_cast<const uint4*>(gsrc + 1024);
        uint4 vb = *reinterpret_cast<const uint4*>(gsrc + 1032);
        *reinterpret_cast<uint4*>(&SM[koff]) = ka;
        *reinterpret_cast<uint4*>(&SM[koff + 8]) = kb;
        uint4 pa, pb;
        pa.x = __shfl_xor(va.x, 4); pa.y = __shfl_xor(va.y, 4);
        pa.z = __shfl_xor(va.z, 4); pa.w = __shfl_xor(va.w, 4);
        pb.x = __shfl_xor(vb.x, 4); pb.y = __shfl_xor(vb.y, 4);
        pb.z = __shfl_xor(vb.z, 4); pb.w = __shfl_xor(vb.w, 4);
        union UU { uint4 v; u16 hh[8]; };
        UU o0, o1, p0u, p1u;
        o0.v = va; o1.v = vb; p0u.v = pa; p1u.v = pb;
        unsigned int* Od = reinterpret_cast<unsigned int*>(SM + 9216);
#pragma unroll
        for (int i = 0; i < 4; ++i) {
            int e = veo + i;
            unsigned int w0 = (skey & 1)
                ? ((unsigned)p0u.hh[e] | ((unsigned)o0.hh[e] << 16))
                : ((unsigned)o0.hh[e] | ((unsigned)p0u.hh[e] << 16));
            unsigned int w1 = (skey & 1)
                ? ((unsigned)p1u.hh[e] | ((unsigned)o1.hh[e] << 16))
                : ((unsigned)o1.hh[e] | ((unsigned)p1u.hh[e] << 16));
            Od[(sseg * 8 + e) * 36 + kp] = w0;
            Od[(sseg * 8 + 8 + e) * 36 + kp] = w1;
        }
    }
    __syncthreads();

    const u16* gnext = gsrc + 64 * C3;
    for (int t = 0; t < nsteps; ++t) {
        const int cur = t & 1;
        const int k0 = t * 64;
        const bool pre = (t + 1 < nsteps);
        uint4 ka = {}, kb = {}, va = {}, vb = {};
        if (pre) {
            ka = *reinterpret_cast<const uint4*>(gnext);
            kb = *reinterpret_cast<const uint4*>(gnext + 8);
            va = *reinterpret_cast<const uint4*>(gnext + 1024);
            vb = *reinterpret_cast<const uint4*>(gnext + 1032);
            gnext += 64 * C3;
        }

        if (k0 <= q0w + 31) {   // wave-uniform validity
            const u16* Kb = SM + cur * 4608;
            const u16* Vb = SM + 9216 + cur * 4608;
            // ---- S^T = K Q^T ----
            f32x16 st0 = {}, st1 = {};
#pragma unroll
            for (int s = 0; s < 4; ++s) {
                short8v kfa = *reinterpret_cast<const short8v*>(&Kb[q31 * 72 + s * 16 + hi * 8]);
                short8v kfb = *reinterpret_cast<const short8v*>(&Kb[(q31 + 32) * 72 + s * 16 + hi * 8]);
                short8v qs = (s == 0) ? qf0 : (s == 1) ? qf1 : (s == 2) ? qf2 : qf3;
                st0 = __builtin_amdgcn_mfma_f32_32x32x16_bf16(kfa, qs, st0, 0, 0, 0);
                st1 = __builtin_amdgcn_mfma_f32_32x32x16_bf16(kfb, qs, st1, 0, 0, 0);
            }
            // ---- causal mask + row max (raw S units) ----
            const bool diag = (k0 + 63 > q0w);
            float s0[16], s1[16];
            float mx = -1e30f;
#pragma unroll
            for (int r = 0; r < 16; ++r) {
                int krel = (r & 3) + 8 * (r >> 2) + 4 * hi;
                float v0 = st0[r];
                float v1 = st1[r];
                if (diag) {
                    if (k0 + krel > qlane) v0 = -1e30f;
                    if (k0 + 32 + krel > qlane) v1 = -1e30f;
                }
                s0[r] = v0; s1[r] = v1;
                mx = fmaxf(mx, fmaxf(v0, v1));
            }
            mx = fmaxf(mx, __shfl_xor(mx, 32));
            // ---- defer-max online softmax (exp2 space) ----
            if (!__all(mx <= m_run + THR)) {
                float m_new = fmaxf(m_run, mx);
                float alpha = exp2g((m_run - m_new) * C2);
                l_run *= alpha;
                acc0 *= alpha;
                acc1 *= alpha;
                m_run = m_new;
            }
            const float mc = m_run * C2;
            float rs = 0.f;
#pragma unroll
            for (int r = 0; r < 16; ++r) {
                float p0 = exp2g(fmaf(s0[r], C2, -mc));
                float p1 = exp2g(fmaf(s1[r], C2, -mc));
                s0[r] = p0; s1[r] = p1;
                rs += p0 + p1;
            }
            rs += __shfl_xor(rs, 32);
            l_run += rs;

            // ---- P -> bf16 B-frags via cvt_pk + permlane32_swap ----
            short8v pf0, pf1, pf2, pf3;
#define MKFRAG(dst, P, rb)                                                  \
            {                                                               \
                unsigned int a_ = pk2(P[rb + 0], P[rb + 1]);                \
                unsigned int b_ = pk2(P[rb + 4], P[rb + 5]);                \
                unsigned int c_ = pk2(P[rb + 2], P[rb + 3]);                \
                unsigned int d_ = pk2(P[rb + 6], P[rb + 7]);                \
                plswap(a_, b_);                                             \
                plswap(c_, d_);                                             \
                union { unsigned int u[4]; short8v s; } uf_;                \
                uf_.u[0] = a_; uf_.u[1] = c_; uf_.u[2] = b_; uf_.u[3] = d_; \
                dst = uf_.s;                                                \
            }
            MKFRAG(pf0, s0, 0)
            MKFRAG(pf1, s0, 8)
            MKFRAG(pf2, s1, 0)
            MKFRAG(pf3, s1, 8)
#undef MKFRAG
            // ---- O^T += V^T P^T ----
#pragma unroll
            for (int s = 0; s < 4; ++s) {
                short8v vfa = *reinterpret_cast<const short8v*>(&Vb[q31 * 72 + s * 16 + hi * 8]);
                short8v vfb = *reinterpret_cast<const short8v*>(&Vb[(q31 + 32) * 72 + s * 16 + hi * 8]);
                short8v ps = (s == 0) ? pf0 : (s == 1) ? pf1 : (s == 2) ? pf2 : pf3;
                acc0 = __builtin_amdgcn_mfma_f32_32x32x16_bf16(vfa, ps, acc0, 0, 0, 0);
                acc1 = __builtin_amdgcn_mfma_f32_32x32x16_bf16(vfb, ps, acc1, 0, 0, 0);
            }
        }

        if (pre) {
            const int nb = cur ^ 1;
            *reinterpret_cast<uint4*>(&SM[nb * 4608 + koff]) = ka;
            *reinterpret_cast<uint4*>(&SM[nb * 4608 + koff + 8]) = kb;
            uint4 pa, pb;
            pa.x = __shfl_xor(va.x, 4); pa.y = __shfl_xor(va.y, 4);
            pa.z = __shfl_xor(va.z, 4); pa.w = __shfl_xor(va.w, 4);
            pb.x = __shfl_xor(vb.x, 4); pb.y = __shfl_xor(vb.y, 4);
            pb.z = __shfl_xor(vb.z, 4); pb.w = __shfl_xor(vb.w, 4);
            union UU { uint4 v; u16 hh[8]; };
            UU o0, o1, p0u, p1u;
            o0.v = va; o1.v = vb; p0u.v = pa; p1u.v = pb;
            unsigned int* Od = reinterpret_cast<unsigned int*>(SM + 9216 + nb * 4608);
#pragma unroll
            for (int i = 0; i < 4; ++i) {
                int e = veo + i;
                unsigned int w0 = (skey & 1)
                    ? ((unsigned)p0u.hh[e] | ((unsigned)o0.hh[e] << 16))
                    : ((unsigned)o0.hh[e] | ((unsigned)p0u.hh[e] << 16));
                unsigned int w1 = (skey & 1)
                    ? ((unsigned)p1u.hh[e] | ((unsigned)o1.hh[e] << 16))
                    : ((unsigned)o1.hh[e] | ((unsigned)p1u.hh[e] << 16));
                Od[(sseg * 8 + e) * 36 + kp] = w0;
                Od[(sseg * 8 + 8 + e) * 36 + kp] = w1;
            }
        }
        __syncthreads();
    }

    // ---- store O: per-wave LDS transpose -> coalesced 16B stores ----
    const float inv = 1.f / l_run;
    unsigned int* Od2 = reinterpret_cast<unsigned int*>(SM);
    const int qrow = w * 32 + q31;
#pragma unroll
    for (int r = 0; r < 16; r += 2) {
        int d0 = (r & 3) + 8 * (r >> 2) + 4 * hi;   // even
        Od2[qrow * 36 + (d0 >> 1)] = pk2(acc0[r] * inv, acc0[r + 1] * inv);
        Od2[qrow * 36 + ((32 + d0) >> 1)] = pk2(acc1[r] * inv, acc1[r + 1] * inv);
    }
    __syncthreads();
    {
        const int row = w * 32 + (l >> 1);
        const int dh = (l & 1) * 32;
        const u16* src = SM + row * 72 + dh;
        const int qtok = chunkw * 64 + (w & 1) * 32 + (l >> 1);
        u16* dst = y + (tok0 + qtok) * Cc + h * 64 + dh;
#pragma unroll
        for (int k2 = 0; k2 < 4; ++k2)
            *reinterpret_cast<uint4*>(dst + k2 * 8) =
                *reinterpret_cast<const uint4*>(src + k2 * 8);
    }
}

extern "C" void kernel_launch(void* const* d_in, const int* in_sizes, int n_in,
                              void* d_out, int out_size, void* d_ws, size_t ws_size,
                              hipStream_t stream) {
    const float* x    = (const float*)d_in[0];
    const float* Wqkv = (const float*)d_in[1];
    const float* Wout = (const float*)d_in[2];
    float* out = (float*)d_out;

    char* ws = (char*)d_ws;
    u16* qkv   = (u16*)(ws);
    u16* xbf   = (u16*)(ws + 50331648);  // aliased as y after GEMM1
    u16* WqkvT = (u16*)(ws + 67108864);
    u16* WoutT = (u16*)(ws + 73400320);

    cvt_x<<<(Mm * Cc) / (256 * 4), 256, 0, stream>>>(x, xbf);
    wtrans<<<dim3(C3 / 32, Cc / 32), 256, 0, stream>>>(Wqkv, WqkvT, Cc, C3);
    wtrans<<<dim3(Cc / 32, Cc / 32), 256, 0, stream>>>(Wout, WoutT, Cc, Cc);

    gemm_mfma<0><<<dim3(Mm / 128, C3 / 128), 256, 0, stream>>>(xbf, WqkvT, qkv, Mm, C3, Cc);

    u16* ybf = xbf;
    attn_mfma<<<Bb * Hh * 16, 256, 0, stream>>>(qkv, ybf);

    gemm_mfma<1><<<dim3(Mm / 128, Cc / 128), 256, 0, stream>>>(ybf, WoutT, out, Mm, Cc, Cc);
}

// Round 7
// 207.780 us; speedup vs baseline: 1.2304x; 1.2304x over previous
//
#include <hip/hip_runtime.h>
#include <hip/hip_bf16.h>

typedef unsigned short u16;
typedef __attribute__((ext_vector_type(8))) short short8v;   // 8 bf16 = 4 VGPR
typedef __attribute__((ext_vector_type(4))) float f32x4;     // mfma 16x16 acc
typedef __attribute__((ext_vector_type(16))) float f32x16;   // mfma 32x32 acc

#define Bb 4
#define Tt 2048
#define Cc 1024
#define Hh 16
#define C3 3072
#define Mm 8192

__device__ __forceinline__ u16 f2bf(float f) {
    union { __hip_bfloat16 h; u16 u; } r;
    r.h = __float2bfloat16(f);
    return r.u;
}
__device__ __forceinline__ unsigned int pk2(float a, float b) {
    union { __hip_bfloat162 h; unsigned int u; } r;
    r.h.x = __float2bfloat16(a);
    r.h.y = __float2bfloat16(b);
    return r.u;
}
__device__ __forceinline__ float exp2g(float x) {
#if __has_builtin(__builtin_amdgcn_exp2f)
    return __builtin_amdgcn_exp2f(x);
#else
    return exp2f(x);
#endif
}
__device__ __forceinline__ void plswap(unsigned int& a, unsigned int& b) {
#if __has_builtin(__builtin_amdgcn_permlane32_swap)
    typedef __attribute__((ext_vector_type(2))) unsigned int uint2v;
    uint2v r = __builtin_amdgcn_permlane32_swap(a, b, false, false);
    a = r.x; b = r.y;
#else
    asm volatile("v_permlane32_swap_b32 %0, %1" : "+v"(a), "+v"(b));
#endif
}
// global -> LDS direct (16B/lane). LDS dest: wave-uniform base + lane*16.
__device__ __forceinline__ void gload16(const void* g, void* l) {
    __builtin_amdgcn_global_load_lds(
        (const __attribute__((address_space(1))) unsigned int*)g,
        (__attribute__((address_space(3))) unsigned int*)l, 16, 0, 0);
}

// ---------- convert x f32 -> bf16 ----------
__global__ __launch_bounds__(256) void cvt_x(const float* __restrict__ in,
                                             u16* __restrict__ out) {
    int i = blockIdx.x * 256 + threadIdx.x;
    float4 v = reinterpret_cast<const float4*>(in)[i];
    ushort4 o;
    o.x = f2bf(v.x); o.y = f2bf(v.y); o.z = f2bf(v.z); o.w = f2bf(v.w);
    reinterpret_cast<ushort4*>(out)[i] = o;
}

// ---------- transpose+convert W [R][Ccols] f32 -> W^T [Ccols][R] bf16 ----------
__global__ __launch_bounds__(256) void wtrans(const float* __restrict__ in,
                                              u16* __restrict__ out,
                                              int R, int Ccols) {
    __shared__ float t[32][33];
    const int tx = threadIdx.x & 31, ty = threadIdx.x >> 5;  // 32x8
    const int bx = blockIdx.x, by = blockIdx.y;
    const int c = bx * 32 + tx;
#pragma unroll
    for (int j = 0; j < 4; ++j) {
        int r = by * 32 + ty + j * 8;
        t[ty + j * 8][tx] = in[(size_t)r * Ccols + c];
    }
    __syncthreads();
#pragma unroll
    for (int j = 0; j < 4; ++j) {
        int orow = bx * 32 + ty + j * 8;
        int oc   = by * 32 + tx;
        out[(size_t)orow * R + oc] = f2bf(t[tx][ty + j * 8]);
    }
}

// ---------- bf16 MFMA GEMM: C[M][N] = A[M][K] * BT[N][K]^T ----------
// MODE 0: bf16 C (stride N). MODE 1: f32 C (stride N).
// MODE 2: qkv split — cols<2048 -> qk[row][col] (stride 2048, bf16);
//         cols>=2048 -> vT[(b*1024 + col-2048)*2048 + t] (V stored transposed).
template <int MODE>
__global__ __launch_bounds__(256) void gemm_mfma(const u16* __restrict__ A,
                                                 const u16* __restrict__ BT,
                                                 void* __restrict__ C0,
                                                 u16* __restrict__ C1,
                                                 int M, int N, int K) {
    __shared__ u16 As[128 * 32];
    __shared__ u16 Bs[128 * 32];
    const int tid = threadIdx.x;
    const int w = tid >> 6, l = tid & 63;
    const int wr = w >> 1, wc = w & 1;
    const int g = l >> 4, q = l & 15;
    const int bm = blockIdx.x * 128, bn = blockIdx.y * 128;
    const int lrow = l >> 2;
    const int lcol = (l & 3) * 8;

    f32x4 acc[4][4] = {};
    const u16* Ap = A + (size_t)(bm + w * 32 + lrow) * K + lcol;
    const u16* Bp = BT + (size_t)(bn + w * 32 + lrow) * K + lcol;

    for (int k0 = 0; k0 < K; k0 += 32) {
        gload16(Ap + k0, &As[(w * 32) * 32]);
        gload16(Ap + (size_t)16 * K + k0, &As[(w * 32 + 16) * 32]);
        gload16(Bp + k0, &Bs[(w * 32) * 32]);
        gload16(Bp + (size_t)16 * K + k0, &Bs[(w * 32 + 16) * 32]);
        __syncthreads();
        short8v af[4], bf[4];
#pragma unroll
        for (int m = 0; m < 4; ++m)
            af[m] = *reinterpret_cast<const short8v*>(&As[(wr * 64 + m * 16 + q) * 32 + g * 8]);
#pragma unroll
        for (int n = 0; n < 4; ++n)
            bf[n] = *reinterpret_cast<const short8v*>(&Bs[(wc * 64 + n * 16 + q) * 32 + g * 8]);
#pragma unroll
        for (int m = 0; m < 4; ++m)
#pragma unroll
            for (int n = 0; n < 4; ++n)
                acc[m][n] = __builtin_amdgcn_mfma_f32_16x16x32_bf16(af[m], bf[n], acc[m][n], 0, 0, 0);
        __syncthreads();
    }

#pragma unroll
    for (int m = 0; m < 4; ++m)
#pragma unroll
        for (int n = 0; n < 4; ++n) {
            const int col = bn + wc * 64 + n * 16 + q;
#pragma unroll
            for (int r = 0; r < 4; ++r) {
                const int row = bm + wr * 64 + m * 16 + g * 4 + r;
                const float v = acc[m][n][r];
                if (MODE == 1) {
                    reinterpret_cast<float*>(C0)[(size_t)row * N + col] = v;
                } else if (MODE == 0) {
                    reinterpret_cast<u16*>(C0)[(size_t)row * N + col] = f2bf(v);
                } else {  // MODE 2
                    if (col < 2048) {
                        reinterpret_cast<u16*>(C0)[(size_t)row * 2048 + col] = f2bf(v);
                    } else {
                        const int bI = row >> 11, tI = row & 2047;
                        C1[((size_t)bI * 1024 + (col - 2048)) * 2048 + tI] = f2bf(v);
                    }
                }
            }
        }
}

// ---------- MFMA flash attention (causal) ----------
// 512 blocks: bh = bid & 63 (XCD-local), c0 = bid >> 6; block does chunk pair
// (c0, 15-c0) in 128-q units, all 4 waves on the same chunk (32 q each).
// KV step = 64 keys. K LDS [64 keys][72] dbuf (from qk);
// V^T LDS [64 d][72 keys] dbuf staged straight from vT (no repack).
__global__ __launch_bounds__(256) void attn_mfma(const u16* __restrict__ qk,
                                                 const u16* __restrict__ vT,
                                                 u16* __restrict__ y) {
    __shared__ u16 SM[18432];   // 36,864 B: K dbuf 2x4608 | V^T dbuf 2x4608
    const int tid = threadIdx.x;
    const int w = tid >> 6, l = tid & 63;
    const int q31 = l & 31, hi = l >> 5;
    const int bid = blockIdx.x;
    const int bh = bid & 63, c0 = bid >> 6;   // same bh -> same XCD (mod-8 dispatch)
    const int b = bh >> 4, h = bh & 15;
    const size_t tok0 = (size_t)b * Tt;

    const float C2 = 0.18033688011112042f;   // 0.125 * log2(e)
    const float THR = 44.361419555836499f;   // 8 / C2 (defer-max)

    // staging ids: 256 thr cover 64 rows x 4 16-col segs
    const int srow = tid >> 2;
    const int sseg = (tid & 3) * 16;
    const int soff = srow * 72 + sseg;
    const u16* gK = qk + (tok0 + srow) * 2048 + 1024 + h * 64 + sseg;
    const u16* gV = vT + ((size_t)b * 1024 + h * 64 + srow) * 2048 + sseg;

    for (int phase = 0; phase < 2; ++phase) {
        const int chunk = phase ? (15 - c0) : c0;
        const int nsteps = 2 * (chunk + 1);
        const int q0w = chunk * 128 + w * 32;
        const int qlane = q0w + q31;

        // Q fragments (mfma B operand): lane holds Q[q=l&31][d = 16s + 8hi + j]
        short8v qf0, qf1, qf2, qf3;
        {
            const u16* qp = qk + (tok0 + qlane) * 2048 + h * 64 + hi * 8;
            qf0 = *reinterpret_cast<const short8v*>(qp);
            qf1 = *reinterpret_cast<const short8v*>(qp + 16);
            qf2 = *reinterpret_cast<const short8v*>(qp + 32);
            qf3 = *reinterpret_cast<const short8v*>(qp + 48);
        }

        f32x16 acc0 = {}, acc1 = {};
        float m_run = -1e30f, l_run = 0.f;

        // ---- prologue: stage tile 0 into buf 0 ----
        {
            uint4 ka = *reinterpret_cast<const uint4*>(gK);
            uint4 kb = *reinterpret_cast<const uint4*>(gK + 8);
            uint4 va = *reinterpret_cast<const uint4*>(gV);
            uint4 vb = *reinterpret_cast<const uint4*>(gV + 8);
            *reinterpret_cast<uint4*>(&SM[soff]) = ka;
            *reinterpret_cast<uint4*>(&SM[soff + 8]) = kb;
            *reinterpret_cast<uint4*>(&SM[9216 + soff]) = va;
            *reinterpret_cast<uint4*>(&SM[9216 + soff + 8]) = vb;
        }
        __syncthreads();

        for (int t = 0; t < nsteps; ++t) {
            const int cur = t & 1;
            const int k0 = t * 64;
            const bool pre = (t + 1 < nsteps);
            uint4 ka = {}, kb = {}, va = {}, vb = {};
            if (pre) {
                const u16* gKt = gK + (size_t)(t + 1) * 64 * 2048;
                const u16* gVt = gV + (t + 1) * 64;
                ka = *reinterpret_cast<const uint4*>(gKt);
                kb = *reinterpret_cast<const uint4*>(gKt + 8);
                va = *reinterpret_cast<const uint4*>(gVt);
                vb = *reinterpret_cast<const uint4*>(gVt + 8);
            }

            if (k0 <= q0w + 31) {   // wave-uniform validity
                const u16* Kb = SM + cur * 4608;
                const u16* Vb = SM + 9216 + cur * 4608;
                // ---- S^T = K Q^T ----
                f32x16 st0 = {}, st1 = {};
#pragma unroll
                for (int s = 0; s < 4; ++s) {
                    short8v kfa = *reinterpret_cast<const short8v*>(&Kb[q31 * 72 + s * 16 + hi * 8]);
                    short8v kfb = *reinterpret_cast<const short8v*>(&Kb[(q31 + 32) * 72 + s * 16 + hi * 8]);
                    short8v qs = (s == 0) ? qf0 : (s == 1) ? qf1 : (s == 2) ? qf2 : qf3;
                    st0 = __builtin_amdgcn_mfma_f32_32x32x16_bf16(kfa, qs, st0, 0, 0, 0);
                    st1 = __builtin_amdgcn_mfma_f32_32x32x16_bf16(kfb, qs, st1, 0, 0, 0);
                }
                // ---- causal mask + row max (raw S units) ----
                const bool diag = (k0 + 63 > q0w);
                float s0[16], s1[16];
                float mx = -1e30f;
#pragma unroll
                for (int r = 0; r < 16; ++r) {
                    int krel = (r & 3) + 8 * (r >> 2) + 4 * hi;
                    float v0 = st0[r];
                    float v1 = st1[r];
                    if (diag) {
                        if (k0 + krel > qlane) v0 = -1e30f;
                        if (k0 + 32 + krel > qlane) v1 = -1e30f;
                    }
                    s0[r] = v0; s1[r] = v1;
                    mx = fmaxf(mx, fmaxf(v0, v1));
                }
                mx = fmaxf(mx, __shfl_xor(mx, 32));
                // ---- defer-max online softmax (exp2 space) ----
                if (!__all(mx <= m_run + THR)) {
                    float m_new = fmaxf(m_run, mx);
                    float alpha = exp2g((m_run - m_new) * C2);
                    l_run *= alpha;
                    acc0 *= alpha;
                    acc1 *= alpha;
                    m_run = m_new;
                }
                const float mc = m_run * C2;
                float rs = 0.f;
#pragma unroll
                for (int r = 0; r < 16; ++r) {
                    float p0 = exp2g(fmaf(s0[r], C2, -mc));
                    float p1 = exp2g(fmaf(s1[r], C2, -mc));
                    s0[r] = p0; s1[r] = p1;
                    rs += p0 + p1;
                }
                rs += __shfl_xor(rs, 32);
                l_run += rs;

                // ---- P -> bf16 B-frags via cvt_pk + permlane32_swap ----
                short8v pf0, pf1, pf2, pf3;
#define MKFRAG(dst, P, rb)                                                  \
                {                                                           \
                    unsigned int a_ = pk2(P[rb + 0], P[rb + 1]);            \
                    unsigned int b_ = pk2(P[rb + 4], P[rb + 5]);            \
                    unsigned int c_ = pk2(P[rb + 2], P[rb + 3]);            \
                    unsigned int d_ = pk2(P[rb + 6], P[rb + 7]);            \
                    plswap(a_, b_);                                         \
                    plswap(c_, d_);                                         \
                    union { unsigned int u[4]; short8v s; } uf_;            \
                    uf_.u[0] = a_; uf_.u[1] = c_; uf_.u[2] = b_; uf_.u[3] = d_; \
                    dst = uf_.s;                                            \
                }
                MKFRAG(pf0, s0, 0)
                MKFRAG(pf1, s0, 8)
                MKFRAG(pf2, s1, 0)
                MKFRAG(pf3, s1, 8)
#undef MKFRAG
                // ---- O^T += V^T P^T ----
#pragma unroll
                for (int s = 0; s < 4; ++s) {
                    short8v vfa = *reinterpret_cast<const short8v*>(&Vb[q31 * 72 + s * 16 + hi * 8]);
                    short8v vfb = *reinterpret_cast<const short8v*>(&Vb[(q31 + 32) * 72 + s * 16 + hi * 8]);
                    short8v ps = (s == 0) ? pf0 : (s == 1) ? pf1 : (s == 2) ? pf2 : pf3;
                    acc0 = __builtin_amdgcn_mfma_f32_32x32x16_bf16(vfa, ps, acc0, 0, 0, 0);
                    acc1 = __builtin_amdgcn_mfma_f32_32x32x16_bf16(vfb, ps, acc1, 0, 0, 0);
                }
            }

            if (pre) {
                const int nb = cur ^ 1;
                *reinterpret_cast<uint4*>(&SM[nb * 4608 + soff]) = ka;
                *reinterpret_cast<uint4*>(&SM[nb * 4608 + soff + 8]) = kb;
                *reinterpret_cast<uint4*>(&SM[9216 + nb * 4608 + soff]) = va;
                *reinterpret_cast<uint4*>(&SM[9216 + nb * 4608 + soff + 8]) = vb;
            }
            __syncthreads();
        }

        // ---- store O: LDS transpose -> coalesced 16B stores ----
        const float inv = 1.f / l_run;
        unsigned int* Od2 = reinterpret_cast<unsigned int*>(SM);
        const int qrow = w * 32 + q31;
#pragma unroll
        for (int r = 0; r < 16; r += 2) {
            int d0 = (r & 3) + 8 * (r >> 2) + 4 * hi;   // even
            Od2[qrow * 36 + (d0 >> 1)] = pk2(acc0[r] * inv, acc0[r + 1] * inv);
            Od2[qrow * 36 + ((32 + d0) >> 1)] = pk2(acc1[r] * inv, acc1[r + 1] * inv);
        }
        __syncthreads();
        {
            const int row = w * 32 + (l >> 1);
            const int dh = (l & 1) * 32;
            const u16* src = SM + row * 72 + dh;
            u16* dst = y + (tok0 + chunk * 128 + row) * Cc + h * 64 + dh;
#pragma unroll
            for (int k2 = 0; k2 < 4; ++k2)
                *reinterpret_cast<uint4*>(dst + k2 * 8) =
                    *reinterpret_cast<const uint4*>(src + k2 * 8);
        }
        __syncthreads();   // protect SM before next phase's staging
    }
}

extern "C" void kernel_launch(void* const* d_in, const int* in_sizes, int n_in,
                              void* d_out, int out_size, void* d_ws, size_t ws_size,
                              hipStream_t stream) {
    const float* x    = (const float*)d_in[0];
    const float* Wqkv = (const float*)d_in[1];
    const float* Wout = (const float*)d_in[2];
    float* out = (float*)d_out;

    // ws layout (bytes):
    //   qk   bf16 [8192][2048]            @ 0        (33,554,432)
    //   vT   bf16 [4][1024 d][2048 t]     @ 33554432 (16,777,216)
    //   x_bf bf16 [8192][1024] (later y)  @ 50331648 (16,777,216)
    //   WqkvT bf16 [3072][1024]           @ 67108864 ( 6,291,456)
    //   WoutT bf16 [1024][1024]           @ 73400320 ( 2,097,152)
    char* ws = (char*)d_ws;
    u16* qk    = (u16*)(ws);
    u16* vT    = (u16*)(ws + 33554432);
    u16* xbf   = (u16*)(ws + 50331648);  // aliased as y after GEMM1
    u16* WqkvT = (u16*)(ws + 67108864);
    u16* WoutT = (u16*)(ws + 73400320);

    cvt_x<<<(Mm * Cc) / (256 * 4), 256, 0, stream>>>(x, xbf);
    wtrans<<<dim3(C3 / 32, Cc / 32), 256, 0, stream>>>(Wqkv, WqkvT, Cc, C3);
    wtrans<<<dim3(Cc / 32, Cc / 32), 256, 0, stream>>>(Wout, WoutT, Cc, Cc);

    gemm_mfma<2><<<dim3(Mm / 128, C3 / 128), 256, 0, stream>>>(xbf, WqkvT, qk, vT, Mm, C3, Cc);

    u16* ybf = xbf;
    attn_mfma<<<512, 256, 0, stream>>>(qk, vT, ybf);

    gemm_mfma<1><<<dim3(Mm / 128, Cc / 128), 256, 0, stream>>>(ybf, WoutT, out, nullptr, Mm, Cc, Cc);
}